// Round 5
// baseline (774.217 us; speedup 1.0000x reference)
//
#include <hip/hip_runtime.h>
#include <hip/hip_bf16.h>
#include <cstdint>
#include <cstddef>

// ---------------- constants ----------------
// B=2 T=1024 H=4096 HK=8 HV=32 DK=64 DV=64 VPK=4
// GEMM1: A[2048][4096] * Wt1[5248(pad 5184)][4096]^T -> qkvz[2048][5184]
// GEMM2: on[2048][2048] * Wt2[4096][2048]^T -> out[2048][4096] (fp32)
// Scan: chunked delta rule via f16 MFMA; units u = (b,hv,chunk) = 1024

typedef __attribute__((ext_vector_type(8))) short short8;
typedef __attribute__((ext_vector_type(4))) float f32x4;
typedef __attribute__((ext_vector_type(4))) _Float16 h4;
typedef __attribute__((ext_vector_type(8))) _Float16 half8;

__device__ __forceinline__ short f2bf(float f) {
  union { float f; unsigned u; } x; x.f = f;
  unsigned r = x.u + 0x7fffu + ((x.u >> 16) & 1u);
  return (short)(r >> 16);
}

__device__ __forceinline__ void gl_lds16(const short* g, short* l) {
  __builtin_amdgcn_global_load_lds(
      (const __attribute__((address_space(1))) void*)g,
      (__attribute__((address_space(3))) void*)l, 16, 0, 0);
}

// A-fragment address (f16 units) for element (m,k) of a 64x64 matrix:
// frag f = (m>>4)*2 + (k>>5); lane = (m&15) + (((k>>3)&3)<<4); j = k&7
__device__ __forceinline__ int fragaddr(int m, int k) {
  return (((m >> 4) * 2 + (k >> 5)) * 64 + ((m & 15) + (((k >> 3) & 3) << 4))) * 8 + (k & 7);
}

// ---------------- elementwise fp32 -> bf16 ----------------
__global__ __launch_bounds__(256) void to_bf16_kernel(const float* __restrict__ x,
                                                      short* __restrict__ y) {
  int i = blockIdx.x * 256 + threadIdx.x;
  float4 v = ((const float4*)x)[i];
  ushort4 r;
  r.x = (unsigned short)f2bf(v.x);
  r.y = (unsigned short)f2bf(v.y);
  r.z = (unsigned short)f2bf(v.z);
  r.w = (unsigned short)f2bf(v.w);
  ((ushort4*)y)[i] = r;
}

// ---------------- transpose+convert W_qkvz|W_ba -> Wt1[n][k], pad to 5248 ----------------
__global__ __launch_bounds__(256) void transpose_w1(const float* __restrict__ Wq,
                                                    const float* __restrict__ Wba,
                                                    short* __restrict__ Wt) {
  __shared__ float tile[32][33];
  int n0 = blockIdx.x * 32;
  int k0 = blockIdx.y * 32;
  int t = threadIdx.x;
  int r = t >> 5;
  int c = t & 31;
#pragma unroll
  for (int i = 0; i < 4; ++i) {
    int kl = r + i * 8;
    int n = n0 + c;
    float v = 0.f;
    if (n < 5120) v = Wq[(size_t)(k0 + kl) * 5120 + n];
    else if (n < 5184) v = Wba[(size_t)(k0 + kl) * 64 + (n - 5120)];
    tile[kl][c] = v;
  }
  __syncthreads();
#pragma unroll
  for (int i = 0; i < 4; ++i) {
    int nl = r + i * 8;
    int kl = c;
    Wt[(size_t)(n0 + nl) * 4096 + k0 + kl] = f2bf(tile[kl][nl]);
  }
}

// ---------------- transpose+convert W_out -> Wt2[n][k] ----------------
__global__ __launch_bounds__(256) void transpose_w2(const float* __restrict__ W,
                                                    short* __restrict__ Wt) {
  __shared__ float tile[32][33];
  int n0 = blockIdx.x * 32;
  int k0 = blockIdx.y * 32;
  int t = threadIdx.x;
  int r = t >> 5;
  int c = t & 31;
#pragma unroll
  for (int i = 0; i < 4; ++i) {
    int kl = r + i * 8;
    tile[kl][c] = W[(size_t)(k0 + kl) * 4096 + n0 + c];
  }
  __syncthreads();
#pragma unroll
  for (int i = 0; i < 4; ++i) {
    int nl = r + i * 8;
    int kl = c;
    Wt[(size_t)(n0 + nl) * 2048 + k0 + kl] = f2bf(tile[kl][nl]);
  }
}

// ---------------- m97-style 128x128 bf16 MFMA GEMM, fp32 out ----------------
template <bool GUARD_N>
__global__ __launch_bounds__(256) void gemm128(const short* __restrict__ A,
                                               const short* __restrict__ Bt,
                                               float* __restrict__ C,
                                               int M, int N, int K) {
  __shared__ __align__(16) short As[128 * 32];
  __shared__ __align__(16) short Bs[128 * 32];
  const int tid = threadIdx.x;
  const int wave = tid >> 6;
  const int lane = tid & 63;
  const int m0 = blockIdx.x * 128;
  const int n0 = blockIdx.y * 128;
  const int wm = (wave >> 1) << 6;
  const int wn = (wave & 1) << 6;

  const int srow = (wave << 4) + (lane >> 2);
  const int scol = (lane & 3) << 3;
  const short* Ag = A + (size_t)(m0 + srow) * K + scol;
  const short* Bg = Bt + (size_t)(n0 + srow) * K + scol;
  const size_t rstep = (size_t)64 * K;

  const int fr = lane & 15;
  const int kq = (lane >> 4) << 3;

  f32x4 acc[4][4];
#pragma unroll
  for (int i = 0; i < 4; ++i)
#pragma unroll
    for (int j = 0; j < 4; ++j) acc[i][j] = (f32x4){0.f, 0.f, 0.f, 0.f};

  for (int k0 = 0; k0 < K; k0 += 32) {
    __syncthreads();
    gl_lds16(Ag + k0,         &As[wave * 512]);
    gl_lds16(Ag + rstep + k0, &As[2048 + wave * 512]);
    gl_lds16(Bg + k0,         &Bs[wave * 512]);
    gl_lds16(Bg + rstep + k0, &Bs[2048 + wave * 512]);
    __syncthreads();
    short8 af[4], bf[4];
#pragma unroll
    for (int i = 0; i < 4; ++i) {
      af[i] = *(const short8*)&As[(wm + i * 16 + fr) * 32 + kq];
      bf[i] = *(const short8*)&Bs[(wn + i * 16 + fr) * 32 + kq];
    }
#pragma unroll
    for (int mt = 0; mt < 4; ++mt)
#pragma unroll
      for (int nt = 0; nt < 4; ++nt)
        acc[mt][nt] = __builtin_amdgcn_mfma_f32_16x16x32_bf16(af[mt], bf[nt], acc[mt][nt], 0, 0, 0);
  }

  const int rbase = (lane >> 4) << 2;
#pragma unroll
  for (int mt = 0; mt < 4; ++mt) {
#pragma unroll
    for (int nt = 0; nt < 4; ++nt) {
      int ncol = n0 + wn + nt * 16 + fr;
      if (GUARD_N && ncol >= N) continue;
      int mrow = m0 + wm + mt * 16 + rbase;
#pragma unroll
      for (int r = 0; r < 4; ++r)
        C[(size_t)(mrow + r) * N + ncol] = acc[mt][nt][r];
    }
  }
}

// ---------------- conv(4-tap causal) + silu + l2norm(q,k) ----------------
__global__ __launch_bounds__(256) void conv_kernel(const float* __restrict__ qkvz,
                                                   const float* __restrict__ conv_w,
                                                   float* __restrict__ mix) {
  __shared__ float sq[1024];
  __shared__ float scale[16];
  int bt = blockIdx.x;
  int t = bt & 1023;
  int tid = threadIdx.x;
  for (int c = tid; c < 3072; c += 256) {
    int col;
    if (c < 512) {
      col = (c >> 6) * 640 + (c & 63);
    } else if (c < 1024) {
      int c2 = c - 512;
      col = (c2 >> 6) * 640 + 64 + (c2 & 63);
    } else {
      int c3 = c - 1024;
      int hv = c3 >> 6;
      col = (hv >> 2) * 640 + 128 + (hv & 3) * 64 + (c3 & 63);
    }
    float acc = 0.f;
#pragma unroll
    for (int j = 0; j < 4; ++j) {
      int tt = t - 3 + j;
      if (tt >= 0) acc += qkvz[(size_t)(bt - 3 + j) * 5184 + col] * conv_w[c * 4 + j];
    }
    float sv = acc / (1.f + __expf(-acc));
    if (c < 1024)
      sq[c] = sv;
    else
      mix[(size_t)bt * 3072 + c] = sv;
  }
  __syncthreads();
  int g = tid >> 4, l = tid & 15;
  float p = 0.f;
#pragma unroll
  for (int i = 0; i < 4; ++i) {
    float v = sq[g * 64 + l * 4 + i];
    p += v * v;
  }
  p += __shfl_xor(p, 1);
  p += __shfl_xor(p, 2);
  p += __shfl_xor(p, 4);
  p += __shfl_xor(p, 8);
  if (l == 0) scale[g] = rsqrtf(p + 1e-6f);
  __syncthreads();
  for (int c = tid; c < 1024; c += 256) {
    float s = scale[c >> 6] * ((c < 512) ? 0.125f : 1.f);
    mix[(size_t)bt * 3072 + c] = sq[c] * s;
  }
}

// ---------------- gates ----------------
__global__ __launch_bounds__(256) void gate_kernel(const float* __restrict__ qkvz,
                                                   const float* __restrict__ dt_bias,
                                                   const float* __restrict__ A_log,
                                                   float* __restrict__ gb,
                                                   float* __restrict__ beta) {
  int i = blockIdx.x * 256 + threadIdx.x;
  int hv = i & 31;
  int bt = i >> 5;
  int hk = hv >> 2, vp = hv & 3;
  const float* row = qkvz + (size_t)bt * 5184 + 5120 + hk * 8;
  float bv = row[vp];
  float av = row[4 + vp];
  float x = av + dt_bias[hv];
  float sp = (x > 20.f) ? x : log1pf(expf(x));
  gb[i] = -expf(A_log[hv]) * sp;
  beta[i] = 1.f / (1.f + expf(-bv));
}

// ---------------- chunked delta-rule precompute -> f16 MFMA fragments ----------------
// Emits per unit u: Wf = -(I+A)^{-1} diag(beta e^c) K  (A-frag f16)
//                   Pf = masked (QK^T) decay            (A-frag f16)
//                   Qf = q * e^{c_t}                     (A-frag f16)
//                   Kf = K^[d][s] = k_s[d] e^{c63-c_s}   (A-frag f16, m=d,k=s)
//                   Rf = (I+A)^{-1} beta V               (C-frag fp32)
//                   ec[u] = e^{c63}
__global__ __launch_bounds__(256) void precompute_kernel(
    const float* __restrict__ mix, const float* __restrict__ gbuf,
    const float* __restrict__ betab, _Float16* __restrict__ Wf,
    _Float16* __restrict__ Pf, _Float16* __restrict__ Qf,
    _Float16* __restrict__ Kf, float* __restrict__ Rf, float* __restrict__ ec) {
  __shared__ float Kt[64][68];   // K col-major: Kt[d][t]; later K' row-major scaled
  __shared__ float Vb[64][68];   // V row-major
  __shared__ float AM[64][68];   // A; later Q col-major
  __shared__ float Mm[64][68];   // (I+A)^{-1}
  __shared__ float Tb[16][17];
  __shared__ float cs[64], bb[64];

  const int u = blockIdx.x;
  const int chunk = u & 15, hv = (u >> 4) & 31, b = u >> 9;
  const int hk = hv >> 2;
  const int t0g = b * 1024 + chunk * 64;
  const int tid = threadIdx.x;
  const int tr = tid >> 2, q4 = tid & 3;
  const size_t ubase = (size_t)u << 12;

  {
    const float* mrow = mix + (size_t)(t0g + tr) * 3072;
#pragma unroll
    for (int e = 0; e < 4; ++e) {
      int c0 = q4 * 16 + e * 4;
      float4 kv = *(const float4*)(mrow + 512 + hk * 64 + c0);
      Kt[c0 + 0][tr] = kv.x; Kt[c0 + 1][tr] = kv.y;
      Kt[c0 + 2][tr] = kv.z; Kt[c0 + 3][tr] = kv.w;
      *(float4*)&Vb[tr][c0] = *(const float4*)(mrow + 1024 + hv * 64 + c0);
    }
  }
  if (tid < 64) {
    cs[tid] = gbuf[(size_t)(t0g + tid) * 32 + hv];
    bb[tid] = betab[(size_t)(t0g + tid) * 32 + hv];
  }
  __syncthreads();
  for (int off = 1; off < 64; off <<= 1) {
    float v = 0.f;
    if (tid < 64 && tid >= off) v = cs[tid - off];
    __syncthreads();
    if (tid < 64) cs[tid] += v;
    __syncthreads();
  }
  if (tid == 0) ec[u] = __expf(cs[63]);

  // A = strictly-lower masked beta_t (k_t.k_s) e^{c_t-c_s}
  {
    float acc[16];
#pragma unroll
    for (int i = 0; i < 16; ++i) acc[i] = 0.f;
    for (int d = 0; d < 64; ++d) {
      float kv = Kt[d][tr];
#pragma unroll
      for (int e = 0; e < 4; ++e) {
        float4 ks = *(const float4*)&Kt[d][q4 * 16 + e * 4];
        acc[e * 4 + 0] += kv * ks.x; acc[e * 4 + 1] += kv * ks.y;
        acc[e * 4 + 2] += kv * ks.z; acc[e * 4 + 3] += kv * ks.w;
      }
    }
    float bt_ = bb[tr], ct_ = cs[tr];
#pragma unroll
    for (int j = 0; j < 16; ++j) {
      int s = q4 * 16 + j;
      AM[tr][s] = (s < tr) ? bt_ * acc[j] * __expf(ct_ - cs[s]) : 0.f;
    }
  }
  __syncthreads();

  // Mm = (I+A)^{-1}
  for (int i = tid; i < 64 * 68; i += 256) (&Mm[0][0])[i] = 0.f;
  __syncthreads();
  if (tid < 64) {
    int blk = tid >> 4, j = tid & 15, base = blk * 16;
    Mm[base][base + j] = (j == 0) ? 1.f : 0.f;
    for (int r = 1; r < 16; ++r) {
      float sum = 0.f;
      for (int s = 0; s < r; ++s) sum += AM[base + r][base + s] * Mm[base + s][base + j];
      Mm[base + r][base + j] = ((r == j) ? 1.f : 0.f) - sum;
    }
  }
  __syncthreads();
  for (int d = 1; d < 4; ++d) {
    for (int j = 0; j + d < 4; ++j) {
      int i = j + d;
      int r = tid >> 4, c = tid & 15;
      float tsum = 0.f;
      for (int kb = j; kb < i; ++kb)
        for (int uu = 0; uu < 16; ++uu)
          tsum += AM[i * 16 + r][kb * 16 + uu] * Mm[kb * 16 + uu][j * 16 + c];
      Tb[r][c] = tsum;
      __syncthreads();
      float msum = 0.f;
      for (int uu = 0; uu < 16; ++uu)
        msum += Mm[i * 16 + r][i * 16 + uu] * Tb[uu][c];
      __syncthreads();
      Mm[i * 16 + r][j * 16 + c] = -msum;
      __syncthreads();
    }
  }

  // stage Q col-major into AM (A is dead)
  {
    const float* mrow = mix + (size_t)(t0g + tr) * 3072 + hk * 64;
#pragma unroll
    for (int e = 0; e < 4; ++e) {
      int c0 = q4 * 16 + e * 4;
      float4 qv = *(const float4*)(mrow + c0);
      AM[c0 + 0][tr] = qv.x; AM[c0 + 1][tr] = qv.y;
      AM[c0 + 2][tr] = qv.z; AM[c0 + 3][tr] = qv.w;
    }
  }
  __syncthreads();

  // P = masked scaled QK^T -> f16 A-frags (m=t, k=s)
  {
    float acc[16];
#pragma unroll
    for (int i = 0; i < 16; ++i) acc[i] = 0.f;
    for (int d = 0; d < 64; ++d) {
      float qv = AM[d][tr];
#pragma unroll
      for (int e = 0; e < 4; ++e) {
        float4 ks = *(const float4*)&Kt[d][q4 * 16 + e * 4];
        acc[e * 4 + 0] += qv * ks.x; acc[e * 4 + 1] += qv * ks.y;
        acc[e * 4 + 2] += qv * ks.z; acc[e * 4 + 3] += qv * ks.w;
      }
    }
    float ct_ = cs[tr];
#pragma unroll
    for (int e = 0; e < 4; ++e) {
      int s0 = q4 * 16 + e * 4;
      h4 pv;
#pragma unroll
      for (int jj = 0; jj < 4; ++jj) {
        int s = s0 + jj;
        float pvf = (s <= tr) ? acc[e * 4 + jj] * __expf(ct_ - cs[s]) : 0.f;
        pv[jj] = (_Float16)pvf;
      }
      *(h4*)&Pf[ubase + fragaddr(tr, s0)] = pv;
    }
  }

  // Qf = q_t e^{c_t} (m=t, k=d); reads AM col (Q col-major)
  {
    float sc = __expf(cs[tr]);
#pragma unroll
    for (int e = 0; e < 4; ++e) {
      int d0 = q4 * 16 + e * 4;
      h4 qv;
#pragma unroll
      for (int jj = 0; jj < 4; ++jj) qv[jj] = (_Float16)(AM[d0 + jj][tr] * sc);
      *(h4*)&Qf[ubase + fragaddr(tr, d0)] = qv;
    }
  }

  // Kf = k_s[d] e^{c63-c_s} (m=d=tr, k=s); reads Kt row (still original col-major K)
  {
    float c63 = cs[63];
#pragma unroll
    for (int e = 0; e < 4; ++e) {
      int s0 = q4 * 16 + e * 4;
      h4 kv;
#pragma unroll
      for (int jj = 0; jj < 4; ++jj)
        kv[jj] = (_Float16)(Kt[tr][s0 + jj] * __expf(c63 - cs[s0 + jj]));
      *(h4*)&Kf[ubase + fragaddr(tr, s0)] = kv;
    }
  }
  __syncthreads();

  // transpose-scale Kt in place: K'[s][k] = Kt_old[k][s] * beta_s * e^{c_s}
  {
    float vals[16];
#pragma unroll
    for (int j = 0; j < 16; ++j) vals[j] = Kt[q4 * 16 + j][tr];
    float sc = bb[tr] * __expf(cs[tr]);
    __syncthreads();
#pragma unroll
    for (int j = 0; j < 16; ++j) Kt[tr][q4 * 16 + j] = vals[j] * sc;
  }
  __syncthreads();

  // Wf = -(Mm * K') (m=t, k=d)
  {
    float acc[16];
#pragma unroll
    for (int i = 0; i < 16; ++i) acc[i] = 0.f;
    for (int s = 0; s < 64; ++s) {
      float m = Mm[tr][s];
#pragma unroll
      for (int e = 0; e < 4; ++e) {
        float4 kk = *(const float4*)&Kt[s][q4 * 16 + e * 4];
        acc[e * 4 + 0] += m * kk.x; acc[e * 4 + 1] += m * kk.y;
        acc[e * 4 + 2] += m * kk.z; acc[e * 4 + 3] += m * kk.w;
      }
    }
#pragma unroll
    for (int e = 0; e < 4; ++e) {
      int k0 = q4 * 16 + e * 4;
      h4 wv = {(_Float16)(-acc[e * 4 + 0]), (_Float16)(-acc[e * 4 + 1]),
               (_Float16)(-acc[e * 4 + 2]), (_Float16)(-acc[e * 4 + 3])};
      *(h4*)&Wf[ubase + fragaddr(tr, k0)] = wv;
    }
  }
  // Rf = Mm * (beta .* V) -> fp32 C-frag layout
  {
    float acc[16];
#pragma unroll
    for (int i = 0; i < 16; ++i) acc[i] = 0.f;
    for (int s = 0; s < 64; ++s) {
      float m = Mm[tr][s] * bb[s];
#pragma unroll
      for (int e = 0; e < 4; ++e) {
        float4 vv = *(const float4*)&Vb[s][q4 * 16 + e * 4];
        acc[e * 4 + 0] += m * vv.x; acc[e * 4 + 1] += m * vv.y;
        acc[e * 4 + 2] += m * vv.z; acc[e * 4 + 3] += m * vv.w;
      }
    }
#pragma unroll
    for (int j = 0; j < 16; ++j) {
      int v = q4 * 16 + j;
      int addr = (((v >> 4) * 4 + (tr >> 4)) << 8) + (((v & 15) + (((tr >> 2) & 3) << 4)) << 2) + (tr & 3);
      Rf[ubase + addr] = acc[j];
    }
  }
}

// ---------------- MFMA chunk scan: 256 single-wave blocks ----------------
// block = (vs, hv, b); wave owns S[64 d][16 v] as 4 fp32 C-frags.
// Per chunk: Delta = (-W)*S + R ; O = P*Delta + Qt*S ; S = e63*S + K^T*Delta.
__global__ __launch_bounds__(64) void chunk_scan_kernel(
    const _Float16* __restrict__ Wf, const _Float16* __restrict__ Pf,
    const _Float16* __restrict__ Qf, const _Float16* __restrict__ Kf,
    const float* __restrict__ Rf, const float* __restrict__ ec,
    float* __restrict__ o) {
  __shared__ _Float16 STl[16][72];
  __shared__ _Float16 DTl[16][72];
  const int bid = blockIdx.x;
  const int vs = bid & 3, hv = (bid >> 2) & 31, b = bid >> 7;
  const int ubase = (b * 32 + hv) * 16;
  const int lane = threadIdx.x;
  const int lv = lane & 15, lg = lane >> 4;

  f32x4 S[4];
#pragma unroll
  for (int mt = 0; mt < 4; ++mt) S[mt] = (f32x4){0.f, 0.f, 0.f, 0.f};

  half8 wr[2][8], pr[2][8], qr[2][8], kr[2][8];
  float4 rr[2][4];
  float e63v[2];

#define LOADU(c, pb)                                                            \
  {                                                                             \
    size_t uu = (size_t)(ubase + (c));                                          \
    const half8* wp = (const half8*)(Wf + (uu << 12));                          \
    const half8* pp = (const half8*)(Pf + (uu << 12));                          \
    const half8* qp = (const half8*)(Qf + (uu << 12));                          \
    const half8* kp = (const half8*)(Kf + (uu << 12));                          \
    _Pragma("unroll") for (int f = 0; f < 8; ++f) {                             \
      wr[pb][f] = wp[f * 64 + lane];                                            \
      pr[pb][f] = pp[f * 64 + lane];                                            \
      qr[pb][f] = qp[f * 64 + lane];                                            \
      kr[pb][f] = kp[f * 64 + lane];                                            \
    }                                                                           \
    _Pragma("unroll") for (int mt = 0; mt < 4; ++mt)                            \
      rr[pb][mt] = *(const float4*)(Rf + (uu << 12) + ((vs * 4 + mt) << 8) + (lane << 2)); \
    e63v[pb] = ec[uu];                                                          \
  }

  LOADU(0, 0);

  for (int c = 0; c < 16; ++c) {
    const int pb = c & 1;
    if (c < 15) LOADU(c + 1, pb ^ 1);

    // ST = S^T as f16
#pragma unroll
    for (int mt = 0; mt < 4; ++mt) {
      h4 sv = {(_Float16)S[mt][0], (_Float16)S[mt][1],
               (_Float16)S[mt][2], (_Float16)S[mt][3]};
      *(h4*)&STl[lv][mt * 16 + lg * 4] = sv;
    }
    half8 stb0 = *(const half8*)&STl[lv][lg * 8];
    half8 stb1 = *(const half8*)&STl[lv][lg * 8 + 32];

    // GEMM-A: Delta = (-W)*S + R
    f32x4 D[4];
#pragma unroll
    for (int mt = 0; mt < 4; ++mt) {
      f32x4 d = {rr[pb][mt].x, rr[pb][mt].y, rr[pb][mt].z, rr[pb][mt].w};
      d = __builtin_amdgcn_mfma_f32_16x16x32_f16(wr[pb][mt * 2 + 0], stb0, d, 0, 0, 0);
      d = __builtin_amdgcn_mfma_f32_16x16x32_f16(wr[pb][mt * 2 + 1], stb1, d, 0, 0, 0);
      D[mt] = d;
    }
    // DT = Delta^T as f16
#pragma unroll
    for (int mt = 0; mt < 4; ++mt) {
      h4 dv = {(_Float16)D[mt][0], (_Float16)D[mt][1],
               (_Float16)D[mt][2], (_Float16)D[mt][3]};
      *(h4*)&DTl[lv][mt * 16 + lg * 4] = dv;
    }
    half8 dtb0 = *(const half8*)&DTl[lv][lg * 8];
    half8 dtb1 = *(const half8*)&DTl[lv][lg * 8 + 32];

    // GEMM-B: O = P*Delta + Qt*S
#pragma unroll
    for (int mt = 0; mt < 4; ++mt) {
      f32x4 oacc = (f32x4){0.f, 0.f, 0.f, 0.f};
      oacc = __builtin_amdgcn_mfma_f32_16x16x32_f16(pr[pb][mt * 2 + 0], dtb0, oacc, 0, 0, 0);
      oacc = __builtin_amdgcn_mfma_f32_16x16x32_f16(pr[pb][mt * 2 + 1], dtb1, oacc, 0, 0, 0);
      oacc = __builtin_amdgcn_mfma_f32_16x16x32_f16(qr[pb][mt * 2 + 0], stb0, oacc, 0, 0, 0);
      oacc = __builtin_amdgcn_mfma_f32_16x16x32_f16(qr[pb][mt * 2 + 1], stb1, oacc, 0, 0, 0);
      float* orow = o + (size_t)(b * 1024 + c * 64 + mt * 16 + lg * 4) * 2048 + hv * 64 + vs * 16 + lv;
      orow[0] = oacc[0];
      orow[2048] = oacc[1];
      orow[4096] = oacc[2];
      orow[6144] = oacc[3];
    }
    // GEMM-C: S = e63*S + K^T*Delta
    float e63 = e63v[pb];
#pragma unroll
    for (int mt = 0; mt < 4; ++mt) {
      f32x4 s = S[mt];
      s[0] *= e63; s[1] *= e63; s[2] *= e63; s[3] *= e63;
      s = __builtin_amdgcn_mfma_f32_16x16x32_f16(kr[pb][mt * 2 + 0], dtb0, s, 0, 0, 0);
      s = __builtin_amdgcn_mfma_f32_16x16x32_f16(kr[pb][mt * 2 + 1], dtb1, s, 0, 0, 0);
      S[mt] = s;
    }
  }
#undef LOADU
}

// ---------------- rmsnorm * norm_w * silu(z), -> bf16 ----------------
__global__ __launch_bounds__(256) void rms_gate_kernel(const float* __restrict__ o,
                                                       const float* __restrict__ qkvz,
                                                       const float* __restrict__ norm_w,
                                                       short* __restrict__ on) {
  int row = blockIdx.x * 4 + (threadIdx.x >> 6);
  int d = threadIdx.x & 63;
  int hv = row & 31;
  int bt = row >> 5;
  int hk = hv >> 2, vp = hv & 3;
  float x = o[(size_t)row * 64 + d];
  float ss = x * x;
  ss += __shfl_xor(ss, 1);
  ss += __shfl_xor(ss, 2);
  ss += __shfl_xor(ss, 4);
  ss += __shfl_xor(ss, 8);
  ss += __shfl_xor(ss, 16);
  ss += __shfl_xor(ss, 32);
  float sc = rsqrtf(ss * (1.f / 64.f) + 1e-5f);
  float z = qkvz[(size_t)bt * 5184 + hk * 640 + 384 + vp * 64 + d];
  float val = x * sc * norm_w[d] * (z / (1.f + __expf(-z)));
  on[(size_t)row * 64 + d] = f2bf(val);
}

// ---------------- launch ----------------
extern "C" void kernel_launch(void* const* d_in, const int* in_sizes, int n_in,
                              void* d_out, int out_size, void* d_ws, size_t ws_size,
                              hipStream_t stream) {
  const float* hidden = (const float*)d_in[0];
  const float* W_qkvz = (const float*)d_in[1];
  const float* W_ba = (const float*)d_in[2];
  const float* conv_w = (const float*)d_in[3];
  const float* dt_bias = (const float*)d_in[4];
  const float* A_log = (const float*)d_in[5];
  const float* norm_w = (const float*)d_in[6];
  const float* W_out = (const float*)d_in[7];
  float* out = (float*)d_out;

  char* ws = (char*)d_ws;
  short* A_bf = (short*)(ws + 0);                // 16,777,216
  short* Wt1 = (short*)(ws + 16777216);          // 42,991,616  [5248][4096]
  short* Wt2 = (short*)(ws + 59768832);          // 16,777,216  [4096][2048]
  float* qkvz = (float*)(ws + 76546048);         // 42,467,328  [2048][5184]
  float* mix = (float*)(ws + 119013376);         // 25,165,824  [2048][3072]
  float* gbuf = (float*)(ws + 144179200);        //    262,144  [2048][32]
  float* beta = (float*)(ws + 144441344);        //    262,144
  float* o = (float*)(ws + 144703488);           // 16,777,216  [2048][2048]
  short* on = (short*)(ws + 161480704);          //  8,388,608  [2048][2048]
  _Float16* Wf = (_Float16*)(ws + 169869312);    //  8,388,608  [1024][4096] f16 frags
  _Float16* Pf = (_Float16*)(ws + 178257920);    //  8,388,608
  _Float16* Qf = (_Float16*)(ws + 186646528);    //  8,388,608
  _Float16* Kf = (_Float16*)(ws + 195035136);    //  8,388,608
  float* Rf = (float*)(ws + 203423744);          // 16,777,216  [1024][4096] f32 C-frags
  float* ecb = (float*)(ws + 220200960);         //      4,096

  to_bf16_kernel<<<8192, 256, 0, stream>>>(hidden, A_bf);
  transpose_w1<<<dim3(164, 128), 256, 0, stream>>>(W_qkvz, W_ba, Wt1);
  transpose_w2<<<dim3(128, 64), 256, 0, stream>>>(W_out, Wt2);
  gemm128<true><<<dim3(16, 41), 256, 0, stream>>>(A_bf, Wt1, qkvz, 2048, 5184, 4096);
  conv_kernel<<<2048, 256, 0, stream>>>(qkvz, conv_w, mix);
  gate_kernel<<<256, 256, 0, stream>>>(qkvz, dt_bias, A_log, gbuf, beta);
  precompute_kernel<<<1024, 256, 0, stream>>>(mix, gbuf, beta, Wf, Pf, Qf, Kf, Rf, ecb);
  chunk_scan_kernel<<<256, 64, 0, stream>>>(Wf, Pf, Qf, Kf, Rf, ecb, o);
  rms_gate_kernel<<<16384, 256, 0, stream>>>(o, qkvz, norm_w, on);
  gemm128<false><<<dim3(16, 32), 256, 0, stream>>>(on, Wt2, out, 2048, 4096, 2048);
}